// Round 1
// baseline (296.714 us; speedup 1.0000x reference)
//
#include <hip/hip_runtime.h>
#include <math.h>

// ---------------- problem constants ----------------
#define NB    256
#define NTOKP 197
#define NTOK  196
#define NC    768
#define NHID  192
#define NH    14
#define NVF   8        // rfft cols = 14/2+1
#define CHT   64       // channels per tile
#define NTILE 12       // 768/64

// twiddles: cos/sin(2*pi*k/14), k=0..13 (compile-time folded under full unroll)
constexpr float CT14[14] = {
    1.0f, 0.9009688679024191f, 0.6234898018587336f, 0.22252093395631445f,
    -0.22252093395631434f, -0.6234898018587335f, -0.9009688679024191f, -1.0f,
    -0.9009688679024191f, -0.6234898018587335f, -0.22252093395631434f,
    0.22252093395631445f, 0.6234898018587336f, 0.9009688679024191f};
constexpr float ST14[14] = {
    0.0f, 0.4338837391175581f, 0.7818314824680298f, 0.9749279121818236f,
    0.9749279121818236f, 0.7818314824680299f, 0.43388373911755823f, 0.0f,
    -0.43388373911755823f, -0.7818314824680299f, -0.9749279121818236f,
    -0.9749279121818236f, -0.7818314824680298f, -0.4338837391175581f};
constexpr float FY2[14] = {0,1,4,9,16,25,36,49,36,25,16,9,4,1};
constexpr float FX2[8]  = {0,1,4,9,16,25,36,49};

// ---------------- K1: LayerNorm stats per (b, token) ----------------
__global__ __launch_bounds__(256) void k_stats(const float* __restrict__ x,
                                               float* __restrict__ meanv,
                                               float* __restrict__ rstdv) {
  int row = blockIdx.x * 4 + (threadIdx.x >> 6);
  int lane = threadIdx.x & 63;
  if (row >= NB * NTOK) return;
  int b = row / NTOK, t = row - b * NTOK;
  const float4* p = (const float4*)(x + ((size_t)b * NTOKP + 1 + t) * NC);
  float s = 0.f, ss = 0.f;
#pragma unroll
  for (int k = 0; k < 3; ++k) {
    float4 v = p[lane + k * 64];
    s += v.x + v.y + v.z + v.w;
    ss += v.x * v.x + v.y * v.y + v.z * v.z + v.w * v.w;
  }
#pragma unroll
  for (int off = 32; off; off >>= 1) {
    s += __shfl_down(s, off);
    ss += __shfl_down(ss, off);
  }
  if (lane == 0) {
    float m = s * (1.f / NC);
    float var = ss * (1.f / NC) - m * m;
    meanv[row] = m;
    rstdv[row] = rsqrtf(var + 1e-5f);
  }
}

// ---------------- stage-B helper (fwd DFT over rows, energy) ----------------
template <int U0, int NU>
__device__ inline void stage_b(const float* __restrict__ A, int c, float& part,
                               float& xmv) {
#pragma unroll
  for (int v = 0; v < NVF; ++v) {
    float sr[NU], si[NU];
#pragma unroll
    for (int k = 0; k < NU; ++k) { sr[k] = 0.f; si[k] = 0.f; }
#pragma unroll
    for (int i = 0; i < NH; ++i) {
      float ar = A[((i * NVF + v) * 2 + 0) * CHT + c];
      float ai = A[((i * NVF + v) * 2 + 1) * CHT + c];
#pragma unroll
      for (int k = 0; k < NU; ++k) {
        int idx = ((U0 + k) * i) % 14;
        sr[k] = fmaf(ar, CT14[idx], fmaf(ai, ST14[idx], sr[k]));
        si[k] = fmaf(ai, CT14[idx], fmaf(-ar, ST14[idx], si[k]));
      }
    }
#pragma unroll
    for (int k = 0; k < NU; ++k) {
      if (U0 == 0 && k == 0 && v == 0) {
        xmv = sr[0] * (1.f / 196.f);  // DC bin -> spatial mean; excluded from energy
      } else {
        part += log1pf(sqrtf(sr[k] * sr[k] + si[k] * si[k]) * (1.f / 14.f));
      }
    }
  }
}

// ---------------- K2: forward DFT + energy + xm ----------------
__global__ __launch_bounds__(256) void k_fwd(const float* __restrict__ x,
                                             const float* __restrict__ gamma,
                                             const float* __restrict__ beta,
                                             const float* __restrict__ meanv,
                                             const float* __restrict__ rstdv,
                                             float* __restrict__ energy,
                                             float* __restrict__ xmv) {
  __shared__ float A[NH * NVF * 2 * CHT];  // [i][v][re/im][c] 57.3 KB
  __shared__ float esum[256];
  int b = blockIdx.y, c0 = blockIdx.x * CHT, tid = threadIdx.x;

  // stage A: A[i,v] = sum_j xn[i,j] e^{-2pi i v j/14}  (tasks: 64c x 14i)
#pragma unroll
  for (int it = 0; it < 4; ++it) {
    int task = tid + it * 256;
    if (task < CHT * NH) {
      int c = task & 63, i = task >> 6;
      float g = gamma[c0 + c], be = beta[c0 + c];
      float ar[NVF] = {}, ai[NVF] = {};
#pragma unroll
      for (int j = 0; j < NH; ++j) {
        int t = i * NH + j;
        float xv = x[((size_t)b * NTOKP + 1 + t) * NC + c0 + c];
        float xn = (xv - meanv[b * NTOK + t]) * rstdv[b * NTOK + t] * g + be;
#pragma unroll
        for (int v = 0; v < NVF; ++v) {
          ar[v] = fmaf(xn, CT14[(v * j) % 14], ar[v]);
          ai[v] = fmaf(-xn, ST14[(v * j) % 14], ai[v]);
        }
      }
#pragma unroll
      for (int v = 0; v < NVF; ++v) {
        A[((i * NVF + v) * 2 + 0) * CHT + c] = ar[v];
        A[((i * NVF + v) * 2 + 1) * CHT + c] = ai[v];
      }
    }
  }
  __syncthreads();

  // stage B: per (c, u-group)
  int c = tid & 63, g = tid >> 6;
  float part = 0.f, xm_local = 0.f;
  switch (g) {
    case 0: stage_b<0, 4>(A, c, part, xm_local); break;
    case 1: stage_b<4, 4>(A, c, part, xm_local); break;
    case 2: stage_b<8, 4>(A, c, part, xm_local); break;
    default: stage_b<12, 2>(A, c, part, xm_local); break;
  }
  esum[tid] = part;
  __syncthreads();
  if (g == 0) {
    float e = esum[c] + esum[c + 64] + esum[c + 128] + esum[c + 192];
    energy[b * NC + c0 + c] = e * (1.f / 112.f);
    xmv[b * NC + c0 + c] = xm_local;
  }
}

// ---------------- K3: per-batch MLP -> m2s = 2*mu^2*sigma + eps ----------------
__global__ __launch_bounds__(256) void k_mlp(const float* __restrict__ energy,
                                             const float* __restrict__ w1,
                                             const float* __restrict__ b1,
                                             const float* __restrict__ w2,
                                             const float* __restrict__ b2,
                                             float* __restrict__ m2s) {
  __shared__ float e[NC];
  __shared__ float hd[NHID];
  int b = blockIdx.x, tid = threadIdx.x;
  for (int k = tid; k < NC; k += 256) e[k] = energy[b * NC + k];
  __syncthreads();
  if (tid < NHID) {
    float acc = b1[tid];
    for (int cc = 0; cc < NC; ++cc) acc = fmaf(e[cc], w1[cc * NHID + tid], acc);
    hd[tid] = 0.5f * acc * (1.f + erff(acc * 0.70710678118654752f));  // exact gelu
  }
  __syncthreads();
  if (tid < 64) {
    float p0 = 0.f, p1 = 0.f;
#pragma unroll
    for (int k = 0; k < 3; ++k) {
      float hv = hd[tid + k * 64];
      p0 = fmaf(hv, w2[2 * (tid + k * 64)], p0);
      p1 = fmaf(hv, w2[2 * (tid + k * 64) + 1], p1);
    }
#pragma unroll
    for (int off = 32; off; off >>= 1) {
      p0 += __shfl_down(p0, off);
      p1 += __shfl_down(p1, off);
    }
    if (tid == 0) {
      float o0 = p0 + b2[0], o1 = p1 + b2[1];
      float muv = 9.899494936611665f / (1.f + expf(-o0));
      muv = fmaxf(muv, 1.f);
      float sp = (o1 > 20.f) ? o1 : log1pf(expf(o1));
      float sg = fmaxf(sp, 0.1f);
      m2s[b] = 2.f * muv * muv * sg + 1e-6f;
    }
  }
}

// ---------------- K4: recompute fwd stage A (centered), circulant filter,
//                      inverse fold, residual + output ----------------
__global__ __launch_bounds__(256) void k_inv(const float* __restrict__ x,
                                             const float* __restrict__ gamma,
                                             const float* __restrict__ beta,
                                             const float* __restrict__ meanv,
                                             const float* __restrict__ rstdv,
                                             const float* __restrict__ xmv,
                                             const float* __restrict__ m2s,
                                             const float* __restrict__ rscale,
                                             float* __restrict__ out) {
  __shared__ float A[NH * NVF * 2 * CHT];  // in-place A -> Z
  __shared__ float mvu[NVF * NH];          // mask[v][u]
  __shared__ float Kv[NVF * NH];           // circulant kernel per v
  int b = blockIdx.y, c0 = blockIdx.x * CHT, tid = threadIdx.x;
  float rs = rscale[0];

  // cls-token passthrough
  if (tid < CHT) {
    size_t idx = (size_t)b * NTOKP * NC + c0 + tid;
    out[idx] = x[idx];
  }

  // mask table
  float ms = m2s[b];
  if (tid < NVF * NH) {
    int u = tid % NH, v = tid / NH;
    mvu[v * NH + u] = expf(-(FY2[u] + FX2[v]) / ms);
  }
  __syncthreads();
  if (tid < NVF * NH) {
    int d = tid % NH, v = tid / NH;
    float s = 0.f;
#pragma unroll
    for (int u = 0; u < NH; ++u) s = fmaf(mvu[v * NH + u], CT14[(u * d) % 14], s);
    Kv[v * NH + d] = s;
  }

  // stage A (centered input: xn - xm)
#pragma unroll
  for (int it = 0; it < 4; ++it) {
    int task = tid + it * 256;
    if (task < CHT * NH) {
      int c = task & 63, i = task >> 6;
      float g = gamma[c0 + c], be = beta[c0 + c];
      float xm = xmv[b * NC + c0 + c];
      float ar[NVF] = {}, ai[NVF] = {};
#pragma unroll
      for (int j = 0; j < NH; ++j) {
        int t = i * NH + j;
        float xv = x[((size_t)b * NTOKP + 1 + t) * NC + c0 + c];
        float xn = (xv - meanv[b * NTOK + t]) * rstdv[b * NTOK + t] * g + be - xm;
#pragma unroll
        for (int v = 0; v < NVF; ++v) {
          ar[v] = fmaf(xn, CT14[(v * j) % 14], ar[v]);
          ai[v] = fmaf(-xn, ST14[(v * j) % 14], ai[v]);
        }
      }
#pragma unroll
      for (int v = 0; v < NVF; ++v) {
        A[((i * NVF + v) * 2 + 0) * CHT + c] = ar[v];
        A[((i * NVF + v) * 2 + 1) * CHT + c] = ai[v];
      }
    }
  }
  __syncthreads();

  // stage Z: per (c,v) column, Z[i] = sum_{i'} A[i']*Kv[(i-i') mod 14] in place
#pragma unroll
  for (int it = 0; it < 2; ++it) {
    int c = tid & 63, v = (tid >> 6) + it * 4;
    float kr[NH];
#pragma unroll
    for (int d = 0; d < NH; ++d) kr[d] = Kv[v * NH + d];
    float ar[NH], ai[NH];
#pragma unroll
    for (int i = 0; i < NH; ++i) {
      ar[i] = A[((i * NVF + v) * 2 + 0) * CHT + c];
      ai[i] = A[((i * NVF + v) * 2 + 1) * CHT + c];
    }
    float zr[NH], zi[NH];
#pragma unroll
    for (int i = 0; i < NH; ++i) {
      zr[i] = 0.f; zi[i] = 0.f;
#pragma unroll
      for (int ip = 0; ip < NH; ++ip) {
        int d = (i - ip + NH) % NH;
        zr[i] = fmaf(ar[ip], kr[d], zr[i]);
        zi[i] = fmaf(ai[ip], kr[d], zi[i]);
      }
    }
#pragma unroll
    for (int i = 0; i < NH; ++i) {
      A[((i * NVF + v) * 2 + 0) * CHT + c] = zr[i];
      A[((i * NVF + v) * 2 + 1) * CHT + c] = zi[i];
    }
  }
  __syncthreads();

  // stage D: inverse over j (Hermitian fold) + residual + store
#pragma unroll
  for (int it = 0; it < 4; ++it) {
    int task = tid + it * 256;
    if (task < CHT * NH) {
      int c = task & 63, i = task >> 6;
      float zr[NVF], zi[NVF];
#pragma unroll
      for (int v = 0; v < NVF; ++v) {
        zr[v] = A[((i * NVF + v) * 2 + 0) * CHT + c];
        zi[v] = A[((i * NVF + v) * 2 + 1) * CHT + c];
      }
      float g = gamma[c0 + c], be = beta[c0 + c];
      float xm = xmv[b * NC + c0 + c];
#pragma unroll
      for (int j = 0; j < NH; ++j) {
        float s = zr[0] + ((j & 1) ? -zr[7] : zr[7]);
#pragma unroll
        for (int v = 1; v < 7; ++v) {
          s = fmaf(2.f * zr[v], CT14[(v * j) % 14], s);
          s = fmaf(-2.f * zi[v], ST14[(v * j) % 14], s);
        }
        int t = i * NH + j;
        size_t idx = ((size_t)b * NTOKP + 1 + t) * NC + c0 + c;
        float xv = x[idx];
        float xn = (xv - meanv[b * NTOK + t]) * rstdv[b * NTOK + t] * g + be;
        float f = s * (1.f / 196.f) + xm;
        out[idx] = xv + rs * (f - xn);
      }
    }
  }
}

extern "C" void kernel_launch(void* const* d_in, const int* in_sizes, int n_in,
                              void* d_out, int out_size, void* d_ws, size_t ws_size,
                              hipStream_t stream) {
  (void)in_sizes; (void)n_in; (void)out_size; (void)ws_size;
  const float* x      = (const float*)d_in[0];
  const float* gamma  = (const float*)d_in[1];
  const float* beta   = (const float*)d_in[2];
  const float* w1     = (const float*)d_in[3];
  const float* b1     = (const float*)d_in[4];
  const float* w2     = (const float*)d_in[5];
  const float* b2     = (const float*)d_in[6];
  const float* rscale = (const float*)d_in[7];
  float* out = (float*)d_out;

  float* wsf    = (float*)d_ws;
  float* meanv  = wsf;                 // 50176
  float* rstdv  = wsf + 50176;         // 50176
  float* energy = wsf + 100352;        // 196608
  float* xmv    = wsf + 296960;        // 196608
  float* m2s    = wsf + 493568;        // 256  (total ~1.93 MB)

  k_stats<<<(NB * NTOK + 3) / 4, 256, 0, stream>>>(x, meanv, rstdv);
  k_fwd<<<dim3(NTILE, NB), 256, 0, stream>>>(x, gamma, beta, meanv, rstdv,
                                             energy, xmv);
  k_mlp<<<NB, 256, 0, stream>>>(energy, w1, b1, w2, b2, m2s);
  k_inv<<<dim3(NTILE, NB), 256, 0, stream>>>(x, gamma, beta, meanv, rstdv, xmv,
                                             m2s, rscale, out);
}

// Round 2
// 170.904 us; speedup vs baseline: 1.7361x; 1.7361x over previous
//
#include <hip/hip_runtime.h>
#include <math.h>

// ---------------- problem constants ----------------
#define NB    256
#define NTOKP 197
#define NTOK  196
#define NC    768
#define NHID  192
#define NH    14
#define NVF   8        // rfft cols = 14/2+1
#define CHT   64       // channels per tile
#define NTILE 12       // 768/64

// twiddles: cos/sin(2*pi*k/14), k=0..13 (compile-time folded under full unroll)
constexpr float CT14[14] = {
    1.0f, 0.9009688679024191f, 0.6234898018587336f, 0.22252093395631445f,
    -0.22252093395631434f, -0.6234898018587335f, -0.9009688679024191f, -1.0f,
    -0.9009688679024191f, -0.6234898018587335f, -0.22252093395631434f,
    0.22252093395631445f, 0.6234898018587336f, 0.9009688679024191f};
constexpr float ST14[14] = {
    0.0f, 0.4338837391175581f, 0.7818314824680298f, 0.9749279121818236f,
    0.9749279121818236f, 0.7818314824680299f, 0.43388373911755823f, 0.0f,
    -0.43388373911755823f, -0.7818314824680299f, -0.9749279121818236f,
    -0.9749279121818236f, -0.7818314824680298f, -0.4338837391175581f};

__device__ __forceinline__ unsigned int pack_bf2(float a, float b) {
  return (__float_as_uint(a) >> 16) | (__float_as_uint(b) & 0xFFFF0000u);
}

// ---------------- K1: LayerNorm stats per (b, token) -> float2(mean, rstd) ----
__global__ __launch_bounds__(256) void k_stats(const float* __restrict__ x,
                                               float2* __restrict__ msv) {
  int row = blockIdx.x * 4 + (threadIdx.x >> 6);
  int lane = threadIdx.x & 63;
  if (row >= NB * NTOK) return;
  int b = row / NTOK, t = row - b * NTOK;
  const float4* p = (const float4*)(x + ((size_t)b * NTOKP + 1 + t) * NC);
  float s = 0.f, ss = 0.f;
#pragma unroll
  for (int k = 0; k < 3; ++k) {
    float4 v = p[lane + k * 64];
    s += v.x + v.y + v.z + v.w;
    ss += v.x * v.x + v.y * v.y + v.z * v.z + v.w * v.w;
  }
#pragma unroll
  for (int off = 32; off; off >>= 1) {
    s += __shfl_down(s, off);
    ss += __shfl_down(ss, off);
  }
  if (lane == 0) {
    float m = s * (1.f / NC);
    float var = ss * (1.f / NC) - m * m;
    msv[row] = make_float2(m, rsqrtf(var + 1e-5f));
  }
}

// ---------------- K2: forward DFT + energy + xm ----------------
__global__ __launch_bounds__(256) void k_fwd(const float* __restrict__ x,
                                             const float* __restrict__ gamma,
                                             const float* __restrict__ beta,
                                             const float2* __restrict__ msv,
                                             float* __restrict__ energy,
                                             float* __restrict__ xmv) {
  __shared__ unsigned int A[NH * NVF * CHT];  // [i][v][c] packed bf16 (re,im) 28.7KB
  __shared__ float2 ms[NTOK];
  __shared__ float esum[256];
  int b = blockIdx.y, c0 = blockIdx.x * CHT, tid = threadIdx.x;
  int c = tid & 63, w = tid >> 6;

  for (int k = tid; k < NTOK; k += 256) ms[k] = msv[b * NTOK + k];
  float g = gamma[c0 + c], be = beta[c0 + c];
  __syncthreads();

  // stage A: per (c,i): A[i,v] = sum_j xn[i,j] e^{-2pi i v j/14}
#pragma unroll 1
  for (int i = w; i < NH; i += 4) {
    const float* xr = x + ((size_t)b * NTOKP + 1 + i * NH) * NC + c0 + c;
    float xn_[NH];
#pragma unroll
    for (int j = 0; j < NH; ++j) {
      float2 m = ms[i * NH + j];
      xn_[j] = (xr[(size_t)j * NC] - m.x) * m.y * g + be;
    }
    float ar[NVF] = {}, ai[NVF] = {};
#pragma unroll
    for (int j = 0; j < NH; ++j) {
#pragma unroll
      for (int v = 0; v < NVF; ++v) {
        ar[v] = fmaf(xn_[j], CT14[(v * j) % 14], ar[v]);
        ai[v] = fmaf(-xn_[j], ST14[(v * j) % 14], ai[v]);
      }
    }
#pragma unroll
    for (int v = 0; v < NVF; ++v) A[(i * NVF + v) * CHT + c] = pack_bf2(ar[v], ai[v]);
  }
  __syncthreads();

  // stage B: per (c, v in {2w, 2w+1}): S[u,v] over u=0..13, accumulate energy
  float part = 0.f, xml = 0.f;
#pragma unroll 1
  for (int vv = 0; vv < 2; ++vv) {
    int v = w * 2 + vv;
    const unsigned int* Ac = A + v * CHT + c;
    float sr[NH], si[NH];
#pragma unroll
    for (int u = 0; u < NH; ++u) { sr[u] = 0.f; si[u] = 0.f; }
#pragma unroll
    for (int i = 0; i < NH; ++i) {
      unsigned int p = Ac[i * NVF * CHT];
      float ar = __uint_as_float(p << 16);
      float ai = __uint_as_float(p & 0xFFFF0000u);
#pragma unroll
      for (int u = 0; u < NH; ++u) {
        int idx = (u * i) % 14;
        sr[u] = fmaf(ar, CT14[idx], fmaf(ai, ST14[idx], sr[u]));
        si[u] = fmaf(ai, CT14[idx], fmaf(-ar, ST14[idx], si[u]));
      }
    }
#pragma unroll
    for (int u = 0; u < NH; ++u) {
      float m2 = sr[u] * sr[u] + si[u] * si[u];
      part += __logf(1.f + __builtin_amdgcn_sqrtf(m2) * (1.f / 14.f));
    }
    if (w == 0 && vv == 0) {  // remove DC bin, extract spatial mean
      xml = sr[0] * (1.f / 196.f);
      part -= __logf(1.f + fabsf(sr[0]) * (1.f / 14.f));
    }
  }
  esum[tid] = part;
  __syncthreads();
  if (w == 0) {
    float e = esum[c] + esum[c + 64] + esum[c + 128] + esum[c + 192];
    energy[b * NC + c0 + c] = e * (1.f / 112.f);
    xmv[b * NC + c0 + c] = xml;
  }
}

// ---------------- K3: per-batch MLP -> m2s = 2*mu^2*sigma + eps ----------------
__global__ __launch_bounds__(256) void k_mlp(const float* __restrict__ energy,
                                             const float* __restrict__ w1,
                                             const float* __restrict__ b1,
                                             const float* __restrict__ w2,
                                             const float* __restrict__ b2,
                                             float* __restrict__ m2s) {
  __shared__ float e[NC];
  __shared__ float hd[NHID];
  int b = blockIdx.x, tid = threadIdx.x;
  for (int k = tid; k < NC; k += 256) e[k] = energy[b * NC + k];
  __syncthreads();
  if (tid < NHID) {
    float acc = b1[tid];
    for (int cc = 0; cc < NC; ++cc) acc = fmaf(e[cc], w1[cc * NHID + tid], acc);
    hd[tid] = 0.5f * acc * (1.f + erff(acc * 0.70710678118654752f));  // exact gelu
  }
  __syncthreads();
  if (tid < 64) {
    float p0 = 0.f, p1 = 0.f;
#pragma unroll
    for (int k = 0; k < 3; ++k) {
      float hv = hd[tid + k * 64];
      p0 = fmaf(hv, w2[2 * (tid + k * 64)], p0);
      p1 = fmaf(hv, w2[2 * (tid + k * 64) + 1], p1);
    }
#pragma unroll
    for (int off = 32; off; off >>= 1) {
      p0 += __shfl_down(p0, off);
      p1 += __shfl_down(p1, off);
    }
    if (tid == 0) {
      float o0 = p0 + b2[0], o1 = p1 + b2[1];
      float muv = 9.899494936611665f / (1.f + expf(-o0));
      muv = fmaxf(muv, 1.f);
      float sp = (o1 > 20.f) ? o1 : log1pf(expf(o1));
      float sg = fmaxf(sp, 0.1f);
      m2s[b] = 2.f * muv * muv * sg + 1e-6f;
    }
  }
}

// ---------------- K4: separable circulant filter + residual ----------------
// mask is separable: exp(-(fy2[u]+fx2[v])/ms) = wexp[u]*wexp[v], so
// filtered = Kc (x) along rows then cols, Kc[d] = (1/14) sum_k wexp[k] cos(2pi k d/14)
__global__ __launch_bounds__(256) void k_inv(const float* __restrict__ x,
                                             const float* __restrict__ gamma,
                                             const float* __restrict__ beta,
                                             const float2* __restrict__ msv,
                                             const float* __restrict__ xmv,
                                             const float* __restrict__ m2s,
                                             const float* __restrict__ rscale,
                                             float* __restrict__ out) {
  __shared__ unsigned int T[NH * 7 * CHT];  // y[i][j'] bf16, j' pairs packed: 25KB
  __shared__ float2 ms[NTOK];
  __shared__ float wexp[NH];
  __shared__ float kc[NH];
  int b = blockIdx.y, c0 = blockIdx.x * CHT, tid = threadIdx.x;
  int c = tid & 63, w = tid >> 6;
  float rs = rscale[0];

  for (int k = tid; k < NTOK; k += 256) ms[k] = msv[b * NTOK + k];
  if (tid < CHT) {  // cls-token passthrough
    size_t idx = (size_t)b * NTOKP * NC + c0 + tid;
    out[idx] = x[idx];
  }
  float msb = m2s[b];
  if (tid < NH) {
    int f = (tid <= 7) ? tid : 14 - tid;
    wexp[tid] = __expf(-(float)(f * f) / msb);
  }
  __syncthreads();
  if (tid < NH) {
    float s = 0.f;
#pragma unroll
    for (int k = 0; k < NH; ++k)
      s = fmaf(wexp[k], __cosf((float)(k * tid) * 0.44879895051282760f), s);
    kc[tid] = s * (1.f / 14.f);
  }
  float g = gamma[c0 + c], be = beta[c0 + c];
  float xm = xmv[b * NC + c0 + c];
  __syncthreads();

  float kr[NH];
#pragma unroll
  for (int d = 0; d < NH; ++d) kr[d] = kc[d];

  // stage 1: per (c,i): y[i,j'] = sum_j (xn[i,j]-xm) * kc[(j'-j) mod 14]
#pragma unroll 1
  for (int i = w; i < NH; i += 4) {
    const float* xr = x + ((size_t)b * NTOKP + 1 + i * NH) * NC + c0 + c;
    float xnc[NH];
#pragma unroll
    for (int j = 0; j < NH; ++j) {
      float2 m = ms[i * NH + j];
      xnc[j] = (xr[(size_t)j * NC] - m.x) * m.y * g + be - xm;
    }
#pragma unroll
    for (int jp = 0; jp < 7; ++jp) {
      float y0 = 0.f, y1 = 0.f;
#pragma unroll
      for (int j = 0; j < NH; ++j) {
        y0 = fmaf(xnc[j], kr[(2 * jp - j + 28) % 14], y0);
        y1 = fmaf(xnc[j], kr[(2 * jp + 1 - j + 28) % 14], y1);
      }
      T[(i * 7 + jp) * CHT + c] = pack_bf2(y0, y1);
    }
  }
  __syncthreads();

  // stage 2: per (c,j'): z[i'] = sum_i y[i,j'] * kc[(i'-i) mod 14]; residual+store
#pragma unroll 1
  for (int jq = w; jq < NH; jq += 4) {
    int jp = jq >> 1, hi = jq & 1;
    float y[NH];
#pragma unroll
    for (int i = 0; i < NH; ++i) {
      unsigned int p = T[(i * 7 + jp) * CHT + c];
      y[i] = __uint_as_float((p >> (16 * hi)) << 16);
    }
    const float* xr = x + ((size_t)b * NTOKP + 1 + jq) * NC + c0 + c;
    float* outr = out + ((size_t)b * NTOKP + 1 + jq) * NC + c0 + c;
#pragma unroll
    for (int ii = 0; ii < NH; ++ii) {
      float z = 0.f;
#pragma unroll
      for (int i = 0; i < NH; ++i) z = fmaf(y[i], kr[(ii - i + 28) % 14], z);
      float xv = xr[(size_t)ii * NH * NC];
      float2 m = ms[ii * NH + jq];
      float xn = (xv - m.x) * m.y * g + be;
      outr[(size_t)ii * NH * NC] = xv + rs * (z + xm - xn);
    }
  }
}

extern "C" void kernel_launch(void* const* d_in, const int* in_sizes, int n_in,
                              void* d_out, int out_size, void* d_ws, size_t ws_size,
                              hipStream_t stream) {
  (void)in_sizes; (void)n_in; (void)out_size; (void)ws_size;
  const float* x      = (const float*)d_in[0];
  const float* gamma  = (const float*)d_in[1];
  const float* beta   = (const float*)d_in[2];
  const float* w1     = (const float*)d_in[3];
  const float* b1     = (const float*)d_in[4];
  const float* w2     = (const float*)d_in[5];
  const float* b2     = (const float*)d_in[6];
  const float* rscale = (const float*)d_in[7];
  float* out = (float*)d_out;

  float* wsf    = (float*)d_ws;
  float2* msv   = (float2*)wsf;        // 50176 float2 = 100352 floats
  float* energy = wsf + 100352;        // 196608
  float* xmv    = wsf + 296960;        // 196608
  float* m2s    = wsf + 493568;        // 256   (total ~1.97 MB)

  k_stats<<<(NB * NTOK + 3) / 4, 256, 0, stream>>>(x, msv);
  k_fwd<<<dim3(NTILE, NB), 256, 0, stream>>>(x, gamma, beta, msv, energy, xmv);
  k_mlp<<<NB, 256, 0, stream>>>(energy, w1, b1, w2, b2, m2s);
  k_inv<<<dim3(NTILE, NB), 256, 0, stream>>>(x, gamma, beta, msv, xmv, m2s,
                                             rscale, out);
}